// Round 14
// baseline (188.209 us; speedup 1.0000x reference)
//
#include <hip/hip_runtime.h>
#include <cstdint>
#include <cstddef>

// ---------------------------------------------------------------------------
// LSTM cell, B=8192, D=H=512, fp32 in/out.
// pre = [x|h] @ Wstack^T + bias ; gates -> c_t, h_t fused in GEMM epilogue.
// Round 17 = resubmit of r16 (round-13 bench died on container acquisition,
// not on the kernel). Champion K-loop untouched; epilogue I/O vectorized
// (G13): each thread handles 4 h-consecutive cells of one m-row ->
// c_prev 1x float4 (was 4 scalars), stores 2x float4 (was 8 scalars),
// ep reads lane-consecutive 16B, bias broadcast. Per-cell math/order
// bit-identical -> absmax must stay 0.015625.
// Session ledger: GEMM FETCH ~33MB == compulsory (r15 refuted cross-kernel
// L2 retention; remap kept, neutral). Six K-loop structural escapes all
// measured negative (8-phase x2, 4blk/CU, fp32-direct, reg-direct,
// dbuf-drain, counted-vmcnt) plus 32x32-MFMA (+4.2M bank conflicts).
// Remaining GEMM gap = 2-barrier stage-drain stall (m233); verified escape
// (m201 8-phase) did not reproduce here (guide's open m232 quadrant).
// ---------------------------------------------------------------------------

typedef __attribute__((ext_vector_type(8))) short short8;   // 8 bf16 = 4 VGPRs
typedef __attribute__((ext_vector_type(4))) float floatx4;  // MFMA acc

#define AS1(p) ((const __attribute__((address_space(1))) void*)(p))
#define AS3(p) ((__attribute__((address_space(3))) void*)(p))

__device__ __forceinline__ unsigned short f2bf(float f) {
  union { float f; unsigned u; } v; v.f = f;
  unsigned u = v.u;
  return (unsigned short)((u + 0x7fffu + ((u >> 16) & 1u)) >> 16);  // RNE
}

// --------------------------- pack everything -------------------------------
// A[b][k] = k<512 ? x[b][k] : h[b][k-512]                  (8192x1024 bf16)
// B[n][k], n = hh*4 + g (h-interleaved gates f,i,g,o), k<512 -> Wx else Wh;
// bias[n] = bx+bh written by the k==0 thread.  8 elems/thread.
struct PackArgs {
  const float* x; const float* h;
  const float* wx[4]; const float* wh[4];
  const float* bx[4]; const float* bh[4];
  unsigned short* A; unsigned short* B; float* bias;
};

__global__ __launch_bounds__(256) void pack_all_kernel(PackArgs P) {
  const int d = blockIdx.x;
  int blk;
  if (d < 4096) {                         // A region: XCD-aligned remap (neutral)
    int p = (d & 7) + ((d >> 10) << 3);   // panel 0..31
    int i = (d >> 3) & 127;
    blk = p * 128 + i;
  } else {
    blk = d;                              // B region unchanged
  }
  const int gid = blk * 256 + threadIdx.x;
  const float* src;
  unsigned short* dst;
  if (gid < 1048576) {                    // ---- A: 8192 rows x 128 chunks ----
    int b = gid >> 7, k = (gid & 127) * 8;
    src = (k < 512) ? (P.x + b * 512 + k) : (P.h + b * 512 + (k - 512));
    dst = P.A + ((size_t)b << 10) + k;
  } else {                                // ---- B: 2048 rows x 128 chunks ----
    int g2 = gid - 1048576;
    int n = g2 >> 7, k = (g2 & 127) * 8;
    int g = n & 3, hh = n >> 2;           // h-interleaved layout
    src = (k < 512) ? (P.wx[g] + hh * 512 + k) : (P.wh[g] + hh * 512 + (k - 512));
    dst = P.B + ((size_t)n << 10) + k;
    if (k == 0) P.bias[n] = P.bx[g][hh] + P.bh[g][hh];
  }
  float4 v0 = ((const float4*)src)[0];
  float4 v1 = ((const float4*)src)[1];
  union { unsigned short us[8]; short8 s; } o;
  o.us[0] = f2bf(v0.x); o.us[1] = f2bf(v0.y);
  o.us[2] = f2bf(v0.z); o.us[3] = f2bf(v0.w);
  o.us[4] = f2bf(v1.x); o.us[5] = f2bf(v1.y);
  o.us[6] = f2bf(v1.z); o.us[7] = f2bf(v1.w);
  *(short8*)dst = o.s;
}

// --------------------------- fused GEMM + LSTM epilogue --------------------
// Grid (32,16): tile = 256 batch x 128 cols (32 hidden x 4 gates). K=1024,
// BK=64. 512 threads = 8 waves; wave tile 64x64 (4x4 frags of 16x16x32).
// LDS: As 32KB @ [0,32768), Bs 16KB @ [32768,49152); epilogue overlays As.
__global__ __launch_bounds__(512, 4)
void lstm_gemm_kernel(const unsigned short* __restrict__ A,   // [8192][1024]
                      const unsigned short* __restrict__ B,   // [2048][1024]
                      const float* __restrict__ bias,         // [2048]
                      const float* __restrict__ c_prev,       // [8192][512]
                      float* __restrict__ h_out,              // [8192][512]
                      float* __restrict__ c_out) {            // [8192][512]
  __shared__ __align__(16) char smem[49152];
  __shared__ __align__(16) float biasS[128];

  const int tid  = threadIdx.x;
  const int lane = tid & 63;
  const int w    = tid >> 6;        // wave 0..7
  const int quad = lane >> 4;
  const int colA = lane & 15;
  const int m0   = blockIdx.x * 256;
  const int n0   = blockIdx.y * 128;    // = 4*h0
  const int h0   = blockIdx.y * 32;

  if (tid < 128) biasS[tid] = bias[n0 + tid];   // contiguous (h-interleave)

  // staging: thread covers tile-row r = j*64 + (tid>>3), 16B chunk (tid&7);
  // global chunk XOR-swizzled by row&7 so ds_read_b128 frags are conflict-free
  const int srow = tid >> 3;        // 0..63
  const int cl   = tid & 7;
  const int cg   = cl ^ (srow & 7);

  floatx4 acc[4][4];
#pragma unroll
  for (int i = 0; i < 4; ++i)
#pragma unroll
    for (int j = 0; j < 4; ++j) acc[i][j] = (floatx4){0.f, 0.f, 0.f, 0.f};

  const int wm = (w >> 1) * 64;     // wave M offset in tile (0,64,128,192)
  const int wn = (w & 1) * 64;      // wave N offset (0 or 64)

  const char* Ag = (const char*)A;
  const char* Bg = (const char*)B;

  for (int kt = 0; kt < 16; ++kt) {
    __syncthreads();                // prior LDS reads done
    const int kb = kt * 128;        // byte offset into 2048-B rows
#pragma unroll
    for (int j = 0; j < 4; ++j) {   // A: 256 rows
      int r = j * 64 + srow;        // tile row 0..255 (r&7 == srow&7)
      __builtin_amdgcn_global_load_lds(
          AS1(Ag + (size_t)(m0 + r) * 2048 + kb + cg * 16),
          AS3(smem + r * 128 + cl * 16), 16, 0, 0);
    }
#pragma unroll
    for (int j = 0; j < 2; ++j) {   // B: 128 rows (h-interleaved)
      int r = j * 64 + srow;        // tile row 0..127
      __builtin_amdgcn_global_load_lds(
          AS1(Bg + (size_t)(n0 + r) * 2048 + kb + cg * 16),
          AS3(smem + 32768 + r * 128 + cl * 16), 16, 0, 0);
    }
    __syncthreads();                // drains vmcnt(0)

#pragma unroll
    for (int kk = 0; kk < 2; ++kk) {
      const int off = ((kk * 4 + quad) ^ (colA & 7)) * 16;
      short8 af[4], bfr[4];
#pragma unroll
      for (int mi = 0; mi < 4; ++mi)
        af[mi] = *(const short8*)(smem + (wm + mi * 16 + colA) * 128 + off);
#pragma unroll
      for (int ni = 0; ni < 4; ++ni)
        bfr[ni] = *(const short8*)(smem + 32768 + (wn + ni * 16 + colA) * 128 + off);
#pragma unroll
      for (int mi = 0; mi < 4; ++mi)
#pragma unroll
        for (int ni = 0; ni < 4; ++ni)
          acc[mi][ni] = __builtin_amdgcn_mfma_f32_16x16x32_bf16(
              af[mi], bfr[ni], acc[mi][ni], 0, 0, 0);
    }
  }

  // ------------------- fused epilogue (4 rounds of 64 M-rows) --------------
  // Thread handles 4 h-consecutive cells of one m-row:
  //   mloc = tid>>3 (0..63), h4 = (tid&7)*4 (0,4,..,28)
  __syncthreads();
  float* ep = (float*)smem;         // [64][132] padded, overlays As
  const int mloc = tid >> 3;
  const int h4   = (tid & 7) * 4;
#pragma unroll
  for (int rd = 0; rd < 4; ++rd) {
    const int m = m0 + rd * 64 + mloc;
    // c_prev hoisted + vectorized: one float4 per thread per round
    float4 cpv = *(const float4*)(c_prev + (size_t)m * 512 + h0 + h4);
    if ((w >> 1) == rd) {           // the 2 waves with wm == rd*64
      // C/D layout: row = quad*4 + rr, col = lane&15
#pragma unroll
      for (int mi = 0; mi < 4; ++mi)
#pragma unroll
        for (int ni = 0; ni < 4; ++ni) {
          int rr0 = mi * 16 + quad * 4;                 // 0..63
          int cc  = wn + ni * 16 + colA;                // 0..127
#pragma unroll
          for (int rr = 0; rr < 4; ++rr)
            ep[(rr0 + rr) * 132 + cc] = acc[mi][ni][rr];
        }
    }
    __syncthreads();
    float hv[4], cvv[4];
    const float* cpp = (const float*)&cpv;
#pragma unroll
    for (int t = 0; t < 4; ++t) {
      int hh = h4 + t;
      // one aligned float4 = (f,i,g,o) pre-activations for this (m,h)
      float4 pre = *(const float4*)(ep + mloc * 132 + hh * 4);
      float4 bb  = *(const float4*)(biasS + hh * 4);
      float pf = pre.x + bb.x;
      float pi = pre.y + bb.y;
      float pg = pre.z + bb.z;
      float po = pre.w + bb.w;
      float fg = 1.f / (1.f + __expf(-pf));
      float ig = 1.f / (1.f + __expf(-pi));
      float gg = 1.f - 2.f / (1.f + __expf(2.f * pg));
      float og = 1.f / (1.f + __expf(-po));
      float cv = fg * cpp[t] + ig * gg;
      float th = 1.f - 2.f / (1.f + __expf(2.f * cv));
      hv[t]  = og * th;
      cvv[t] = cv;
    }
    *(float4*)(h_out + (size_t)m * 512 + h0 + h4) =
        (float4){hv[0], hv[1], hv[2], hv[3]};
    *(float4*)(c_out + (size_t)m * 512 + h0 + h4) =
        (float4){cvv[0], cvv[1], cvv[2], cvv[3]};
    __syncthreads();
  }
}

// ---------------------------------------------------------------------------
extern "C" void kernel_launch(void* const* d_in, const int* in_sizes, int n_in,
                              void* d_out, int out_size, void* d_ws, size_t ws_size,
                              hipStream_t stream) {
  // workspace: A_bf16 (16 MiB) | B_bf16 (4 MiB) | bias (8 KiB)
  char* ws = (char*)d_ws;
  unsigned short* Abf = (unsigned short*)ws;
  unsigned short* Bbf = (unsigned short*)(ws + (size_t)16777216);
  float* bias = (float*)(ws + (size_t)16777216 + 4194304);

  float* hout = (float*)d_out;
  float* cout = hout + (size_t)8192 * 512;

  PackArgs P;
  P.x = (const float*)d_in[0];
  P.h = (const float*)d_in[1];
  // gate order: 0=f, 1=i, 2=g(cell), 3=o
  P.wx[0] = (const float*)d_in[3];  P.bx[0] = (const float*)d_in[4];
  P.wh[0] = (const float*)d_in[5];  P.bh[0] = (const float*)d_in[6];
  P.wx[1] = (const float*)d_in[7];  P.bx[1] = (const float*)d_in[8];
  P.wh[1] = (const float*)d_in[9];  P.bh[1] = (const float*)d_in[10];
  P.wx[2] = (const float*)d_in[11]; P.bx[2] = (const float*)d_in[12];
  P.wh[2] = (const float*)d_in[13]; P.bh[2] = (const float*)d_in[14];
  P.wx[3] = (const float*)d_in[15]; P.bx[3] = (const float*)d_in[16];
  P.wh[3] = (const float*)d_in[17]; P.bh[3] = (const float*)d_in[18];
  P.A = Abf; P.B = Bbf; P.bias = bias;

  // A: 1048576 threads + B: 262144 threads = 5120 blocks of 256
  pack_all_kernel<<<5120, 256, 0, stream>>>(P);

  const float* c = (const float*)d_in[2];
  dim3 grid(32, 16);
  lstm_gemm_kernel<<<grid, 512, 0, stream>>>(Abf, Bbf, bias, c, hout, cout);
}

// Round 15
// 167.723 us; speedup vs baseline: 1.1221x; 1.1221x over previous
//
#include <hip/hip_runtime.h>
#include <cstdint>
#include <cstddef>

// ---------------------------------------------------------------------------
// LSTM cell, B=8192, D=H=512, fp32 in/out.
// pre = [x|h] @ Wstack^T + bias ; gates -> c_t, h_t fused in GEMM epilogue.
// Round 18 = FINAL: byte-exact restore of the verified champion (r15 form;
// measured GEMM 46.8-47.6us, totals 164.8-170.2 across three runs).
// r17's float4-store epilogue REGRESSED (GEMM 75us): 8 write streams 2KB
// apart per wave-instruction defeated L2 write-combining -> RFO (+12.6MB
// FETCH) + write amplification (+24.5MB WRITE). The scalar-store epilogue's
// 2-contiguous-segments-per-wave pattern is the right one on this chip:
// store-stream locality per instruction > per-thread vector width.
// Session ledger: seven K-loop/shape rewrites measured negative (8-phase x2,
// 4blk/CU, fp32-direct, reg-direct, dbuf-drain, counted-vmcnt, 32x32-MFMA);
// wins were epilogue grafts (+2.4us), pack width (+2.5us). GEMM FETCH ~33MB
// == compulsory. Remaining gap = 2-barrier stage-drain stall (m233);
// its verified escape (m201) did not reproduce (guide's open m232 quadrant).
// ---------------------------------------------------------------------------

typedef __attribute__((ext_vector_type(8))) short short8;   // 8 bf16 = 4 VGPRs
typedef __attribute__((ext_vector_type(4))) float floatx4;  // MFMA acc

#define AS1(p) ((const __attribute__((address_space(1))) void*)(p))
#define AS3(p) ((__attribute__((address_space(3))) void*)(p))

__device__ __forceinline__ unsigned short f2bf(float f) {
  union { float f; unsigned u; } v; v.f = f;
  unsigned u = v.u;
  return (unsigned short)((u + 0x7fffu + ((u >> 16) & 1u)) >> 16);  // RNE
}

// --------------------------- pack everything -------------------------------
// A[b][k] = k<512 ? x[b][k] : h[b][k-512]                  (8192x1024 bf16)
// B[n][k], n = hh*4 + g (h-interleaved gates f,i,g,o), k<512 -> Wx else Wh;
// bias[n] = bx+bh written by the k==0 thread.  8 elems/thread.
struct PackArgs {
  const float* x; const float* h;
  const float* wx[4]; const float* wh[4];
  const float* bx[4]; const float* bh[4];
  unsigned short* A; unsigned short* B; float* bias;
};

__global__ __launch_bounds__(256) void pack_all_kernel(PackArgs P) {
  const int d = blockIdx.x;
  int blk;
  if (d < 4096) {                         // A region: XCD-aligned remap (neutral)
    int p = (d & 7) + ((d >> 10) << 3);   // panel 0..31
    int i = (d >> 3) & 127;
    blk = p * 128 + i;
  } else {
    blk = d;                              // B region unchanged
  }
  const int gid = blk * 256 + threadIdx.x;
  const float* src;
  unsigned short* dst;
  if (gid < 1048576) {                    // ---- A: 8192 rows x 128 chunks ----
    int b = gid >> 7, k = (gid & 127) * 8;
    src = (k < 512) ? (P.x + b * 512 + k) : (P.h + b * 512 + (k - 512));
    dst = P.A + ((size_t)b << 10) + k;
  } else {                                // ---- B: 2048 rows x 128 chunks ----
    int g2 = gid - 1048576;
    int n = g2 >> 7, k = (g2 & 127) * 8;
    int g = n & 3, hh = n >> 2;           // h-interleaved layout
    src = (k < 512) ? (P.wx[g] + hh * 512 + k) : (P.wh[g] + hh * 512 + (k - 512));
    dst = P.B + ((size_t)n << 10) + k;
    if (k == 0) P.bias[n] = P.bx[g][hh] + P.bh[g][hh];
  }
  float4 v0 = ((const float4*)src)[0];
  float4 v1 = ((const float4*)src)[1];
  union { unsigned short us[8]; short8 s; } o;
  o.us[0] = f2bf(v0.x); o.us[1] = f2bf(v0.y);
  o.us[2] = f2bf(v0.z); o.us[3] = f2bf(v0.w);
  o.us[4] = f2bf(v1.x); o.us[5] = f2bf(v1.y);
  o.us[6] = f2bf(v1.z); o.us[7] = f2bf(v1.w);
  *(short8*)dst = o.s;
}

// --------------------------- fused GEMM + LSTM epilogue --------------------
// Grid (32,16): tile = 256 batch x 128 cols (32 hidden x 4 gates). K=1024,
// BK=64. 512 threads = 8 waves; wave tile 64x64 (4x4 frags of 16x16x32).
// LDS: As 32KB @ [0,32768), Bs 16KB @ [32768,49152); epilogue overlays As.
__global__ __launch_bounds__(512, 4)
void lstm_gemm_kernel(const unsigned short* __restrict__ A,   // [8192][1024]
                      const unsigned short* __restrict__ B,   // [2048][1024]
                      const float* __restrict__ bias,         // [2048]
                      const float* __restrict__ c_prev,       // [8192][512]
                      float* __restrict__ h_out,              // [8192][512]
                      float* __restrict__ c_out) {            // [8192][512]
  __shared__ __align__(16) char smem[49152];
  __shared__ __align__(16) float biasS[128];

  const int tid  = threadIdx.x;
  const int lane = tid & 63;
  const int w    = tid >> 6;        // wave 0..7
  const int quad = lane >> 4;
  const int colA = lane & 15;
  const int m0   = blockIdx.x * 256;
  const int n0   = blockIdx.y * 128;    // = 4*h0
  const int h0   = blockIdx.y * 32;

  if (tid < 128) biasS[tid] = bias[n0 + tid];   // contiguous (h-interleave)

  // staging: thread covers tile-row r = j*64 + (tid>>3), 16B chunk (tid&7);
  // global chunk XOR-swizzled by row&7 so ds_read_b128 frags are conflict-free
  const int srow = tid >> 3;        // 0..63
  const int cl   = tid & 7;
  const int cg   = cl ^ (srow & 7);

  floatx4 acc[4][4];
#pragma unroll
  for (int i = 0; i < 4; ++i)
#pragma unroll
    for (int j = 0; j < 4; ++j) acc[i][j] = (floatx4){0.f, 0.f, 0.f, 0.f};

  const int wm = (w >> 1) * 64;     // wave M offset in tile (0,64,128,192)
  const int wn = (w & 1) * 64;      // wave N offset (0 or 64)

  const char* Ag = (const char*)A;
  const char* Bg = (const char*)B;

  for (int kt = 0; kt < 16; ++kt) {
    __syncthreads();                // prior LDS reads done
    const int kb = kt * 128;        // byte offset into 2048-B rows
#pragma unroll
    for (int j = 0; j < 4; ++j) {   // A: 256 rows
      int r = j * 64 + srow;        // tile row 0..255 (r&7 == srow&7)
      __builtin_amdgcn_global_load_lds(
          AS1(Ag + (size_t)(m0 + r) * 2048 + kb + cg * 16),
          AS3(smem + r * 128 + cl * 16), 16, 0, 0);
    }
#pragma unroll
    for (int j = 0; j < 2; ++j) {   // B: 128 rows (h-interleaved)
      int r = j * 64 + srow;        // tile row 0..127
      __builtin_amdgcn_global_load_lds(
          AS1(Bg + (size_t)(n0 + r) * 2048 + kb + cg * 16),
          AS3(smem + 32768 + r * 128 + cl * 16), 16, 0, 0);
    }
    __syncthreads();                // drains vmcnt(0)

#pragma unroll
    for (int kk = 0; kk < 2; ++kk) {
      const int off = ((kk * 4 + quad) ^ (colA & 7)) * 16;
      short8 af[4], bfr[4];
#pragma unroll
      for (int mi = 0; mi < 4; ++mi)
        af[mi] = *(const short8*)(smem + (wm + mi * 16 + colA) * 128 + off);
#pragma unroll
      for (int ni = 0; ni < 4; ++ni)
        bfr[ni] = *(const short8*)(smem + 32768 + (wn + ni * 16 + colA) * 128 + off);
#pragma unroll
      for (int mi = 0; mi < 4; ++mi)
#pragma unroll
        for (int ni = 0; ni < 4; ++ni)
          acc[mi][ni] = __builtin_amdgcn_mfma_f32_16x16x32_bf16(
              af[mi], bfr[ni], acc[mi][ni], 0, 0, 0);
    }
  }

  // ------------------- fused epilogue (4 rounds of 64 M-rows) --------------
  __syncthreads();
  float* ep = (float*)smem;         // [64][132] padded, overlays As
#pragma unroll
  for (int rd = 0; rd < 4; ++rd) {
    // c_prev hoisted: HBM latency hides under ep writes + barrier
    float cp[4];
#pragma unroll
    for (int j = 0; j < 4; ++j) {
      int idx  = j * 512 + tid;     // 0..2047
      int mloc = idx >> 5;
      int hh   = idx & 31;
      cp[j] = c_prev[(m0 + rd * 64 + mloc) * 512 + h0 + hh];
    }
    if ((w >> 1) == rd) {           // the 2 waves with wm == rd*64
      // C/D layout: row = quad*4 + rr, col = lane&15
#pragma unroll
      for (int mi = 0; mi < 4; ++mi)
#pragma unroll
        for (int ni = 0; ni < 4; ++ni) {
          int rr0 = mi * 16 + quad * 4;                 // 0..63
          int cc  = wn + ni * 16 + colA;                // 0..127
#pragma unroll
          for (int rr = 0; rr < 4; ++rr)
            ep[(rr0 + rr) * 132 + cc] = acc[mi][ni][rr];
        }
    }
    __syncthreads();
#pragma unroll
    for (int j = 0; j < 4; ++j) {
      int idx  = j * 512 + tid;     // 0..2047
      int mloc = idx >> 5;
      int hh   = idx & 31;
      // one aligned float4 = (f,i,g,o) pre-activations for this (m,h)
      float4 pre = *(const float4*)(ep + mloc * 132 + hh * 4);
      float4 bb  = *(const float4*)(biasS + hh * 4);
      float pf = pre.x + bb.x;
      float pi = pre.y + bb.y;
      float pg = pre.z + bb.z;
      float po = pre.w + bb.w;
      float fg = 1.f / (1.f + __expf(-pf));
      float ig = 1.f / (1.f + __expf(-pi));
      float gg = 1.f - 2.f / (1.f + __expf(2.f * pg));
      float og = 1.f / (1.f + __expf(-po));
      float cv = fg * cp[j] + ig * gg;
      float th = 1.f - 2.f / (1.f + __expf(2.f * cv));
      int m  = m0 + rd * 64 + mloc;
      int hg = h0 + hh;
      h_out[m * 512 + hg] = og * th;
      c_out[m * 512 + hg] = cv;
    }
    __syncthreads();
  }
}

// ---------------------------------------------------------------------------
extern "C" void kernel_launch(void* const* d_in, const int* in_sizes, int n_in,
                              void* d_out, int out_size, void* d_ws, size_t ws_size,
                              hipStream_t stream) {
  // workspace: A_bf16 (16 MiB) | B_bf16 (4 MiB) | bias (8 KiB)
  char* ws = (char*)d_ws;
  unsigned short* Abf = (unsigned short*)ws;
  unsigned short* Bbf = (unsigned short*)(ws + (size_t)16777216);
  float* bias = (float*)(ws + (size_t)16777216 + 4194304);

  float* hout = (float*)d_out;
  float* cout = hout + (size_t)8192 * 512;

  PackArgs P;
  P.x = (const float*)d_in[0];
  P.h = (const float*)d_in[1];
  // gate order: 0=f, 1=i, 2=g(cell), 3=o
  P.wx[0] = (const float*)d_in[3];  P.bx[0] = (const float*)d_in[4];
  P.wh[0] = (const float*)d_in[5];  P.bh[0] = (const float*)d_in[6];
  P.wx[1] = (const float*)d_in[7];  P.bx[1] = (const float*)d_in[8];
  P.wh[1] = (const float*)d_in[9];  P.bh[1] = (const float*)d_in[10];
  P.wx[2] = (const float*)d_in[11]; P.bx[2] = (const float*)d_in[12];
  P.wh[2] = (const float*)d_in[13]; P.bh[2] = (const float*)d_in[14];
  P.wx[3] = (const float*)d_in[15]; P.bx[3] = (const float*)d_in[16];
  P.wh[3] = (const float*)d_in[17]; P.bh[3] = (const float*)d_in[18];
  P.A = Abf; P.B = Bbf; P.bias = bias;

  // A: 1048576 threads + B: 262144 threads = 5120 blocks of 256
  pack_all_kernel<<<5120, 256, 0, stream>>>(P);

  const float* c = (const float*)d_in[2];
  dim3 grid(32, 16);
  lstm_gemm_kernel<<<grid, 512, 0, stream>>>(Abf, Bbf, bias, c, hout, cout);
}